// Round 6
// baseline (110.015 us; speedup 1.0000x reference)
//
#include <hip/hip_runtime.h>
#include <cmath>

#define DEV __device__ __forceinline__

// ---------------- parameter structs (filled host-side in double) ----------------
struct F1C { float a, r0, shift, rlow, rhigh, blow, rclow, bhigh, rchigh; };
struct F2C { float k, r0, dc2, rlow, rhigh, blow, rclow, bhigh, rchigh; };
struct F3C { float sigma2, rstar2, b, rc, rc2; };
struct F4C { float a, t0, ts, b, tc; };
struct F5P { float a, xs, xc, b; };

struct Params {
  F1C f1_stck, f1_hb;
  F2C f2_crst, f2_cx;
  F3C f3_back, f3_base, f3_mix;
  // dedup: s6=s5, h2=h3=c4=h1, h8=h7, c3=c2, c8=c7, x4=s4
  F4C s4, s5, h1, h4, h7, c1, c2, c7, x1;
  F5P f5;
  // padded compaction windows, SQUARED (gates on r^2, sqrt-free common phase)
  float nlo1sq, nhi1sq, nlo2sq, nhi2sq;
};

// ---------------- fast native ops (single instruction) ----------------
DEV float asqrt(float x) { return __builtin_amdgcn_sqrtf(x); }   // v_sqrt_f32
DEV float arcp(float x)  { return __builtin_amdgcn_rcpf(x); }    // v_rcp_f32
DEV float arsq(float x)  { return __builtin_amdgcn_rsqf(x); }    // v_rsq_f32

// ---------------- small vector helpers ----------------
struct V3 { float x, y, z; };
DEV V3 operator+(V3 a, V3 b) { return {a.x + b.x, a.y + b.y, a.z + b.z}; }
DEV V3 operator-(V3 a, V3 b) { return {a.x - b.x, a.y - b.y, a.z - b.z}; }
DEV V3 operator*(float s, V3 a) { return {s * a.x, s * a.y, s * a.z}; }
DEV float dot(V3 a, V3 b) { return a.x * b.x + a.y * b.y + a.z * b.z; }

DEV V3 mim(V3 d, V3 box, V3 ibox) {  // min_image, jnp.round == rint (half-to-even)
  return { d.x - box.x * rintf(d.x * ibox.x),
           d.y - box.y * rintf(d.y * ibox.y),
           d.z - box.z * rintf(d.z * ibox.z) };
}

DEV void quat_a1(float4 q, V3& a1) {
  float w = q.x, x = q.y, y = q.z, z = q.w;
  a1 = { w*w + x*x - y*y - z*z, 2.f*(x*y + w*z), 2.f*(x*z - w*y) };
}

DEV void quat_a23(float4 q, V3& a2, V3& a3) {
  float w = q.x, x = q.y, y = q.z, z = q.w;
  a2 = { 2.f*(x*y - w*z), w*w - x*x + y*y - z*z, 2.f*(y*z + w*x) };
  a3 = { 2.f*(x*z + w*y), 2.f*(y*z - w*x), w*w - x*x - y*y + z*z };
}

// acos(clip(c, -1+1e-6, 1-1e-6)), A&S 4.4.46 minimax, |err| <= 2e-8 rad.
// p(1) sums to sqrt(2) so the sqrt(1-u) endpoint behavior is exact.
DEV float acosc(float x) {
  x = fminf(fmaxf(x, -0.999999f), 0.999999f);
  float u = fabsf(x);
  float p = -0.0012624911f;
  p = fmaf(p, u,  0.0066700901f);
  p = fmaf(p, u, -0.0170881256f);
  p = fmaf(p, u,  0.0308918810f);
  p = fmaf(p, u, -0.0501743046f);
  p = fmaf(p, u,  0.0889789874f);
  p = fmaf(p, u, -0.2145988016f);
  p = fmaf(p, u,  1.5707963050f);
  float r = asqrt(1.f - u) * p;
  return x >= 0.f ? r : 3.14159265358979f - r;
}

// ---------------- the smoothed potential pieces ----------------
DEV float f1f(float r, const F1C& c) {
  if (r <= c.rclow || r >= c.rchigh) return 0.f;
  if (r < c.rlow) { float d = r - c.rclow; return c.blow * d * d; }
  if (r < c.rhigh) {
    float ex = __expf(-c.a * (r - c.r0));   // native exp2-based
    float t = 1.f - ex;
    return t * t - c.shift;
  }
  float d = r - c.rchigh; return c.bhigh * d * d;
}

DEV float f2f(float r, const F2C& c) {
  if (r <= c.rclow || r >= c.rchigh) return 0.f;
  if (r < c.rlow) { float d = r - c.rclow; return c.blow * d * d; }
  if (r < c.rhigh) { float d = r - c.r0; return 0.5f * c.k * (d * d - c.dc2); }
  float d = r - c.rchigh; return c.bhigh * d * d;
}

// sqrt-free unless in the narrow smoothing shell (gates on r^2; monotone since all >0)
DEV float f3f(float r2, const F3C& c, float eps) {
  if (r2 >= c.rc2) return 0.f;
  float v;
  if (r2 < c.rstar2) {
    float t = c.sigma2 * arcp(r2);  // (sigma/r)^2
    float x6 = t * t * t;           // (sigma/r)^6
    v = 4.f * (x6 * x6 - x6);
  } else {
    float d = asqrt(r2) - c.rc; v = c.b * d * d;
  }
  return eps * v;
}

DEV float f4f(float th, const F4C& c) {
  float dt = fabsf(th - c.t0);
  if (dt >= c.tc) return 0.f;
  if (dt < c.ts) return 1.f - c.a * dt * dt;
  float d = c.tc - dt; return c.b * d * d;
}

DEV float f5f(float x, const F5P& c) {
  if (x <= c.xc) return 0.f;
  if (x > 0.f) return 1.f;
  if (x > c.xs) return 1.f - c.a * x * x;
  float d = c.xc - x; return c.b * d * d;
}

// ---------------- fused kernel: common part + in-block LDS compaction ----------
// No global atomics (round-3 lesson: single-address device atomicAdd from 17K
// waves serialized = +154us). Compaction stays inside the block (round-5: OK).
__global__ void __launch_bounds__(256)
energy_kernel(const float* __restrict__ pos,
              const float4* __restrict__ quat,
              const float* __restrict__ boxp,
              const float* __restrict__ seps,
              const float* __restrict__ hbm,
              const float* __restrict__ exclp,
              const int2* __restrict__ bp,
              const int2* __restrict__ nbp,
              const int* __restrict__ btype,
              int M, int NP, Params P,
              double* __restrict__ partials)
{
  int gid = blockIdx.x * 256 + threadIdx.x;
  float bx = boxp[0], by = boxp[1], bz = boxp[2];
  V3 box = { bx, by, bz };
  V3 ibox = { arcp(bx), arcp(by), arcp(bz) };

  float e = 0.f;
  bool need = false;
  int2 myij = {0, 0};
  if (gid < M + NP) {
    bool isNB = gid < M;
    myij = isNB ? nbp[gid] : bp[gid - M];
    float excl = exclp[0];

    const float* pi_ = pos + 3 * myij.x;
    const float* pj_ = pos + 3 * myij.y;
    V3 dp = { pj_[0] - pi_[0], pj_[1] - pi_[1], pj_[2] - pi_[2] };
    float4 qi = quat[myij.x], qj = quat[myij.y];
    V3 a1i, a1j;
    quat_a1(qi, a1i);           // common phase needs a1 only (a2/a3 deferred)
    quat_a1(qj, a1j);

    V3 s = a1j - a1i;           // equal-site terms
    V3 t = a1j + a1i;           // cross-site terms
    V3 dbb = mim(dp - 0.4f  * s, box, ibox);  // back-back
    V3 dhh = mim(dp + 0.4f  * s, box, ibox);  // base-base
    V3 dbB = mim(dp + 0.4f  * t, box, ibox);  // back(i)-base(j)
    V3 dBb = mim(dp - 0.4f  * t, box, ibox);  // base(i)-back(j)
    V3 dss = mim(dp + 0.34f * s, box, ibox);  // stack-stack

    float rbb2 = dot(dbb, dbb) + 1e-12f;
    float rhh2 = dot(dhh, dhh) + 1e-12f;
    float rbB2 = dot(dbB, dbB) + 1e-12f;
    float rBb2 = dot(dBb, dBb) + 1e-12f;
    float rss2 = dot(dss, dss) + 1e-12f;

    // excluded volume shared by bonded (e_bexc) and nonbonded (e_nexc) — sqrt-free
    e += f3f(rhh2, P.f3_base, excl);
    e += f3f(rbB2, P.f3_mix,  excl);
    e += f3f(rBb2, P.f3_mix,  excl);

    if (isNB) {
      e += f3f(rbb2, P.f3_back, excl);
      // padded squared windows: spurious inclusion contributes exactly 0 later
      need = (rhh2 > P.nlo1sq && rhh2 < P.nhi1sq) ||
             (rss2 > P.nlo2sq && rss2 < P.nhi2sq);
    } else {
      float rsbb = arsq(rbb2);
      float rbb  = rbb2 * rsbb;        // r = r^2 * rsq(r^2)
      // FENE: -0.5*eps*log1p(-arg), eps=2 -> -log(1-arg); delta=0.25 -> *4
      float u = (rbb - 0.7525f) * 4.0f;
      float arg = fminf(u * u, 0.999999f);
      e += -__logf(1.f - arg);
      // stacking
      float rsss = arsq(rss2);
      float rss  = rss2 * rsss;
      float f1v = f1f(rss, P.f1_stck);
      if (f1v != 0.f) {
        V3 a2i, a3i, a2j, a3j;
        quat_a23(qi, a2i, a3i);
        quat_a23(qj, a2j, a3j);
        V3 rhs = rsss * dss;
        V3 rhb = rsbb * dbb;
        float th4 = acosc( dot(a3i, a3j));
        float th5 = acosc( dot(rhs, a3j));
        float th6 = acosc(-dot(rhs, a3i));
        e += seps[gid - M] * f1v * f4f(th4, P.s4) * f4f(th5, P.s5) * f4f(th6, P.s5)
                           * f5f(dot(a2i, rhb), P.f5) * f5f(dot(a2j, rhb), P.f5);
      }
    }
  }

  // ---- in-block compaction of angle-needing NB pairs (atomic-free) ----
  __shared__ unsigned wcnt[4];
  __shared__ int2 spair[256];
  int lane = threadIdx.x & 63, wid = threadIdx.x >> 6;
  unsigned long long mask = __ballot(need);
  if (lane == 0) wcnt[wid] = (unsigned)__popcll(mask);
  __syncthreads();
  unsigned base = 0;
  #pragma unroll
  for (int w = 0; w < 4; ++w) if (w < wid) base += wcnt[w];
  unsigned total = wcnt[0] + wcnt[1] + wcnt[2] + wcnt[3];
  if (need) {
    unsigned pfx = (unsigned)__popcll(mask & ((1ull << lane) - 1ull));
    spair[base + pfx] = myij;
  }
  __syncthreads();

  // ---- dense angle phase: ~all lanes useful ----
  for (unsigned t = threadIdx.x; t < total; t += 256) {
    int2 ij = spair[t];
    const float* pi_ = pos + 3 * ij.x;
    const float* pj_ = pos + 3 * ij.y;
    V3 dp = { pj_[0] - pi_[0], pj_[1] - pi_[1], pj_[2] - pi_[2] };
    float4 qi = quat[ij.x], qj = quat[ij.y];
    V3 a1i, a2i, a3i, a1j, a2j, a3j;
    quat_a1(qi, a1i);  quat_a23(qi, a2i, a3i);
    quat_a1(qj, a1j);  quat_a23(qj, a2j, a3j);
    V3 s = a1j - a1i;
    V3 dhh = mim(dp + 0.4f  * s, box, ibox);
    V3 dss = mim(dp + 0.34f * s, box, ibox);
    float rhh2 = dot(dhh, dhh) + 1e-12f;
    float rss2 = dot(dss, dss) + 1e-12f;
    float rsh = arsq(rhh2);
    float rhh = rhh2 * rsh;

    float t1 = acosc(-dot(a1i, a1j));
    float t4 = acosc( dot(a3i, a3j));

    V3 rh = rsh * dhh;
    float t2 = acosc(-dot(rh, a1j));
    float t3 = acosc( dot(rh, a1i));
    float t7 = acosc(-dot(rh, a3j));
    float t8 = acosc( dot(rh, a3i));

    float f1v = f1f(rhh, P.f1_hb);
    if (f1v != 0.f) {
      float eps = hbm[btype[ij.x] * 4 + btype[ij.y]];
      e += eps * f1v * f4f(t1, P.h1) * f4f(t2, P.h1) * f4f(t3, P.h1)
               * f4f(t4, P.h4) * f4f(t7, P.h7) * f4f(t8, P.h7);
    }
    float f2v = f2f(rhh, P.f2_crst);
    if (f2v != 0.f)
      e += f2v * f4f(t1, P.c1) * f4f(t2, P.c2) * f4f(t3, P.c2)
               * f4f(t4, P.h1) * f4f(t7, P.c7) * f4f(t8, P.c7);

    float rsx = arsq(rss2);
    float rss = rss2 * rsx;
    float f2x = f2f(rss, P.f2_cx);
    if (f2x != 0.f) {
      V3 rx = rsx * dss;
      e += f2x * f4f(t1, P.x1) * f4f(t4, P.s4)
               * f5f(dot(a2i, rx), P.f5) * f5f(dot(a2j, rx), P.f5);
    }
  }

  // deterministic block reduction in double
  double v = (double)e;
  #pragma unroll
  for (int off = 32; off > 0; off >>= 1) v += __shfl_down(v, off, 64);
  __shared__ double sm[4];
  if (lane == 0) sm[wid] = v;
  __syncthreads();
  if (threadIdx.x == 0) partials[blockIdx.x] = sm[0] + sm[1] + sm[2] + sm[3];
}

__global__ void __launch_bounds__(1024)
finalize_kernel(const double* __restrict__ part, int n, float* __restrict__ out) {
  double v = 0.0;
  for (int i = threadIdx.x; i < n; i += 1024) v += part[i];
  #pragma unroll
  for (int off = 32; off > 0; off >>= 1) v += __shfl_down(v, off, 64);
  __shared__ double sm[16];
  int lane = threadIdx.x & 63, wid = threadIdx.x >> 6;
  if (lane == 0) sm[wid] = v;
  __syncthreads();
  if (wid == 0) {
    v = (lane < 16) ? sm[lane] : 0.0;
    #pragma unroll
    for (int off = 8; off > 0; off >>= 1) v += __shfl_down(v, off, 64);
    if (lane == 0) out[0] = (float)v;
  }
}

// ---------------- host-side constant construction (double precision) ----------------
static inline double sqd(double x) { return x * x; }

static F1C mkf1(double a, double r0, double rc, double rlow, double rhigh) {
  double shift = sqd(1.0 - exp(-a * (rc - r0)));
  double el = exp(-a * (rlow - r0)), eh = exp(-a * (rhigh - r0));
  double Vl = sqd(1.0 - el) - shift, Vh = sqd(1.0 - eh) - shift;
  double dVl = 2.0 * (1.0 - el) * a * el, dVh = 2.0 * (1.0 - eh) * a * eh;
  double rclow = rlow - 2.0 * Vl / dVl, blow = dVl * dVl / (4.0 * Vl);
  double rchigh = rhigh - 2.0 * Vh / dVh, bhigh = dVh * dVh / (4.0 * Vh);
  return { (float)a, (float)r0, (float)shift, (float)rlow, (float)rhigh,
           (float)blow, (float)rclow, (float)bhigh, (float)rchigh };
}

static F2C mkf2(double k, double r0, double rc, double rlow, double rhigh) {
  double dc2 = sqd(rc - r0);
  double Vl = 0.5 * k * (sqd(rlow - r0) - dc2), Vh = 0.5 * k * (sqd(rhigh - r0) - dc2);
  double dVl = k * (rlow - r0), dVh = k * (rhigh - r0);
  double rclow = rlow - 2.0 * Vl / dVl, blow = dVl * dVl / (4.0 * Vl);
  double rchigh = rhigh - 2.0 * Vh / dVh, bhigh = dVh * dVh / (4.0 * Vh);
  return { (float)k, (float)r0, (float)dc2, (float)rlow, (float)rhigh,
           (float)blow, (float)rclow, (float)bhigh, (float)rchigh };
}

static F3C mkf3(double sigma, double rstar) {
  double s6 = pow(sigma, 6.0);
  double V = 4.0 * (s6 * s6 / pow(rstar, 12.0) - s6 / pow(rstar, 6.0));
  double dV = 4.0 * (-12.0 * s6 * s6 / pow(rstar, 13.0) + 6.0 * s6 / pow(rstar, 7.0));
  double rc = rstar - 2.0 * V / dV, b = dV * dV / (4.0 * V);
  return { (float)(sigma * sigma), (float)(rstar * rstar), (float)b,
           (float)rc, (float)(rc * rc) };
}

static F4C mkf4(double a, double t0, double ts) {
  double b = a * a * ts * ts / (1.0 - a * ts * ts);
  double tc = ts + a * ts / b;
  return { (float)a, (float)t0, (float)ts, (float)b, (float)tc };
}

static F5P mkf5(double a, double xs) {
  double V = 1.0 - a * xs * xs, dV = -2.0 * a * xs;
  double xc = xs - 2.0 * V / dV, b = dV * dV / (4.0 * V);
  return { (float)a, (float)xs, (float)xc, (float)b };
}

extern "C" void kernel_launch(void* const* d_in, const int* in_sizes, int n_in,
                              void* d_out, int out_size, void* d_ws, size_t ws_size,
                              hipStream_t stream) {
  (void)n_in; (void)out_size; (void)ws_size;
  const double PI = 3.141592653589793;

  const float*  pos  = (const float*)d_in[0];
  const float4* quat = (const float4*)d_in[1];
  const float*  box  = (const float*)d_in[2];
  const float*  seps = (const float*)d_in[3];
  const float*  hbm  = (const float*)d_in[4];
  const float*  excl = (const float*)d_in[5];
  const int2*   bp   = (const int2*)d_in[6];
  const int2*   nbp  = (const int2*)d_in[7];
  const int*    bt   = (const int*)d_in[8];

  int NP = in_sizes[6] / 2;     // bonded pairs
  int M  = in_sizes[7] / 2;     // nonbonded pairs
  int total = M + NP;
  int blocks = (total + 255) / 256;

  Params P;
  P.f1_stck = mkf1(6.0, 0.4, 0.9, 0.32, 0.75);
  P.f1_hb   = mkf1(8.0, 0.4, 0.75, 0.34, 0.7);
  P.f2_crst = mkf2(47.5, 0.575, 0.675, 0.495, 0.655);
  P.f2_cx   = mkf2(46.0, 0.4, 0.6, 0.22, 0.58);
  P.f3_back = mkf3(0.7, 0.675);
  P.f3_base = mkf3(0.33, 0.32);
  P.f3_mix  = mkf3(0.515, 0.5);
  P.s4 = mkf4(1.3, 0.0, 0.8);
  P.s5 = mkf4(0.9, 0.0, 0.95);
  P.h1 = mkf4(1.5, 0.0, 0.7);
  P.h4 = mkf4(0.46, PI, 0.7);
  P.h7 = mkf4(4.0, 0.5 * PI, 0.45);
  P.c1 = mkf4(2.25, 0.791, 0.58);
  P.c2 = mkf4(1.7, 1.003, 0.68);
  P.c7 = mkf4(1.7, 0.555, 0.68);
  P.x1 = mkf4(2.0, 2.592, 0.65);
  P.f5 = mkf5(2.0, -0.65);
  // compaction windows, padded then squared (gates compare against r^2)
  {
    double lo1 = (double)P.f1_hb.rclow  - 1e-3, hi1 = (double)P.f1_hb.rchigh + 1e-3;
    double lo2 = (double)P.f2_cx.rclow  - 1e-3, hi2 = (double)P.f2_cx.rchigh + 1e-3;
    P.nlo1sq = (float)(lo1 * lo1);  P.nhi1sq = (float)(hi1 * hi1);
    P.nlo2sq = (float)(lo2 * lo2);  P.nhi2sq = (float)(hi2 * hi2);
  }

  double* partials = (double*)d_ws;

  energy_kernel<<<blocks, 256, 0, stream>>>(pos, quat, box, seps, hbm, excl,
                                            bp, nbp, bt, M, NP, P, partials);
  finalize_kernel<<<1, 1024, 0, stream>>>(partials, blocks, (float*)d_out);
}

// Round 7
// 106.082 us; speedup vs baseline: 1.0371x; 1.0371x over previous
//
#include <hip/hip_runtime.h>
#include <cmath>

#define DEV __device__ __forceinline__

// ---------------- parameter structs (filled host-side in double) ----------------
struct F1C { float a, r0, shift, rlow, rhigh, blow, rclow, bhigh, rchigh; };
struct F2C { float k, r0, dc2, rlow, rhigh, blow, rclow, bhigh, rchigh; };
struct F3C { float sigma2, rstar2, b, rc, rc2; };
struct F4C { float a, t0, ts, b, tc; };
struct F5P { float a, xs, xc, b; };

struct Params {
  F1C f1_stck, f1_hb;
  F2C f2_crst, f2_cx;
  F3C f3_back, f3_base, f3_mix;
  // dedup: s6=s5, h2=h3=c4=h1, h8=h7, c3=c2, c8=c7, x4=s4
  F4C s4, s5, h1, h4, h7, c1, c2, c7, x1;
  F5P f5;
  // padded compaction windows, SQUARED (gates on r^2, sqrt-free common phase)
  float nlo1sq, nhi1sq, nlo2sq, nhi2sq;
};

// ---------------- fast native ops (single instruction) ----------------
DEV float asqrt(float x) { return __builtin_amdgcn_sqrtf(x); }   // v_sqrt_f32
DEV float arcp(float x)  { return __builtin_amdgcn_rcpf(x); }    // v_rcp_f32
DEV float arsq(float x)  { return __builtin_amdgcn_rsqf(x); }    // v_rsq_f32

// ---------------- small vector helpers ----------------
struct V3 { float x, y, z; };
DEV V3 operator+(V3 a, V3 b) { return {a.x + b.x, a.y + b.y, a.z + b.z}; }
DEV V3 operator-(V3 a, V3 b) { return {a.x - b.x, a.y - b.y, a.z - b.z}; }
DEV V3 operator*(float s, V3 a) { return {s * a.x, s * a.y, s * a.z}; }
DEV float dot(V3 a, V3 b) { return a.x * b.x + a.y * b.y + a.z * b.z; }

DEV V3 mim(V3 d, V3 box, V3 ibox) {  // min_image, jnp.round == rint (half-to-even)
  return { d.x - box.x * rintf(d.x * ibox.x),
           d.y - box.y * rintf(d.y * ibox.y),
           d.z - box.z * rintf(d.z * ibox.z) };
}

DEV void quat_a1(float4 q, V3& a1) {
  float w = q.x, x = q.y, y = q.z, z = q.w;
  a1 = { w*w + x*x - y*y - z*z, 2.f*(x*y + w*z), 2.f*(x*z - w*y) };
}

DEV void quat_a23(float4 q, V3& a2, V3& a3) {
  float w = q.x, x = q.y, y = q.z, z = q.w;
  a2 = { 2.f*(x*y - w*z), w*w - x*x + y*y - z*z, 2.f*(y*z + w*x) };
  a3 = { 2.f*(x*z + w*y), 2.f*(y*z - w*x), w*w - x*x - y*y + z*z };
}

// acos(clip(c, -1+1e-6, 1-1e-6)), A&S 4.4.46 minimax, |err| <= 2e-8 rad.
DEV float acosc(float x) {
  x = fminf(fmaxf(x, -0.999999f), 0.999999f);
  float u = fabsf(x);
  float p = -0.0012624911f;
  p = fmaf(p, u,  0.0066700901f);
  p = fmaf(p, u, -0.0170881256f);
  p = fmaf(p, u,  0.0308918810f);
  p = fmaf(p, u, -0.0501743046f);
  p = fmaf(p, u,  0.0889789874f);
  p = fmaf(p, u, -0.2145988016f);
  p = fmaf(p, u,  1.5707963050f);
  float r = asqrt(1.f - u) * p;
  return x >= 0.f ? r : 3.14159265358979f - r;
}

// ---------------- the smoothed potential pieces ----------------
DEV float f1f(float r, const F1C& c) {
  if (r <= c.rclow || r >= c.rchigh) return 0.f;
  if (r < c.rlow) { float d = r - c.rclow; return c.blow * d * d; }
  if (r < c.rhigh) {
    float ex = __expf(-c.a * (r - c.r0));
    float t = 1.f - ex;
    return t * t - c.shift;
  }
  float d = r - c.rchigh; return c.bhigh * d * d;
}

DEV float f2f(float r, const F2C& c) {
  if (r <= c.rclow || r >= c.rchigh) return 0.f;
  if (r < c.rlow) { float d = r - c.rclow; return c.blow * d * d; }
  if (r < c.rhigh) { float d = r - c.r0; return 0.5f * c.k * (d * d - c.dc2); }
  float d = r - c.rchigh; return c.bhigh * d * d;
}

// sqrt-free unless in the narrow smoothing shell (gates on r^2; monotone since all >0)
DEV float f3f(float r2, const F3C& c, float eps) {
  if (r2 >= c.rc2) return 0.f;
  float v;
  if (r2 < c.rstar2) {
    float t = c.sigma2 * arcp(r2);  // (sigma/r)^2
    float x6 = t * t * t;           // (sigma/r)^6
    v = 4.f * (x6 * x6 - x6);
  } else {
    float d = asqrt(r2) - c.rc; v = c.b * d * d;
  }
  return eps * v;
}

DEV float f4f(float th, const F4C& c) {
  float dt = fabsf(th - c.t0);
  if (dt >= c.tc) return 0.f;
  if (dt < c.ts) return 1.f - c.a * dt * dt;
  float d = c.tc - dt; return c.b * d * d;
}

DEV float f5f(float x, const F5P& c) {
  if (x <= c.xc) return 0.f;
  if (x > 0.f) return 1.f;
  if (x > c.xs) return 1.f - c.a * x * x;
  float d = c.xc - x; return c.b * d * d;
}

// ---------------- pack kernel: 32B-aligned per-particle record ----------------
// rec[2*i]   = {pos.x, pos.y, pos.z, btype_as_float}
// rec[2*i+1] = quat
// One guaranteed-aligned L2 line per particle touch in the gather-heavy kernel
// (vs pos 12B-stride scalar loads straddling lines + separate quat array).
__global__ void __launch_bounds__(256)
pack_kernel(const float* __restrict__ pos,
            const float4* __restrict__ quat,
            const int* __restrict__ btype,
            int N, float4* __restrict__ rec)
{
  int i = blockIdx.x * 256 + threadIdx.x;
  if (i < N) {
    rec[2*i]   = { pos[3*i], pos[3*i+1], pos[3*i+2], __int_as_float(btype[i]) };
    rec[2*i+1] = quat[i];
  }
}

// ---------------- fused kernel: common part + in-block LDS compaction ----------
// No global atomics (round-3 lesson). Compaction stays inside the block.
__global__ void __launch_bounds__(256)
energy_kernel(const float4* __restrict__ rec,
              const float* __restrict__ boxp,
              const float* __restrict__ seps,
              const float* __restrict__ hbm,
              const float* __restrict__ exclp,
              const int2* __restrict__ bp,
              const int2* __restrict__ nbp,
              int M, int NP, Params P,
              double* __restrict__ partials)
{
  int gid = blockIdx.x * 256 + threadIdx.x;
  float bx = boxp[0], by = boxp[1], bz = boxp[2];
  V3 box = { bx, by, bz };
  V3 ibox = { arcp(bx), arcp(by), arcp(bz) };

  float e = 0.f;
  bool need = false;
  int2 myij = {0, 0};
  if (gid < M + NP) {
    bool isNB = gid < M;
    myij = isNB ? nbp[gid] : bp[gid - M];
    float excl = exclp[0];

    float4 pi4 = rec[2*myij.x], qi = rec[2*myij.x+1];
    float4 pj4 = rec[2*myij.y], qj = rec[2*myij.y+1];
    V3 dp = { pj4.x - pi4.x, pj4.y - pi4.y, pj4.z - pi4.z };
    V3 a1i, a1j;
    quat_a1(qi, a1i);           // common phase needs a1 only (a2/a3 deferred)
    quat_a1(qj, a1j);

    V3 s = a1j - a1i;           // equal-site terms
    V3 t = a1j + a1i;           // cross-site terms
    V3 dbb = mim(dp - 0.4f  * s, box, ibox);  // back-back
    V3 dhh = mim(dp + 0.4f  * s, box, ibox);  // base-base
    V3 dbB = mim(dp + 0.4f  * t, box, ibox);  // back(i)-base(j)
    V3 dBb = mim(dp - 0.4f  * t, box, ibox);  // base(i)-back(j)
    V3 dss = mim(dp + 0.34f * s, box, ibox);  // stack-stack

    float rbb2 = dot(dbb, dbb) + 1e-12f;
    float rhh2 = dot(dhh, dhh) + 1e-12f;
    float rbB2 = dot(dbB, dbB) + 1e-12f;
    float rBb2 = dot(dBb, dBb) + 1e-12f;
    float rss2 = dot(dss, dss) + 1e-12f;

    // excluded volume shared by bonded (e_bexc) and nonbonded (e_nexc) — sqrt-free
    e += f3f(rhh2, P.f3_base, excl);
    e += f3f(rbB2, P.f3_mix,  excl);
    e += f3f(rBb2, P.f3_mix,  excl);

    if (isNB) {
      e += f3f(rbb2, P.f3_back, excl);
      // padded squared windows: spurious inclusion contributes exactly 0 later
      need = (rhh2 > P.nlo1sq && rhh2 < P.nhi1sq) ||
             (rss2 > P.nlo2sq && rss2 < P.nhi2sq);
    } else {
      float rsbb = arsq(rbb2);
      float rbb  = rbb2 * rsbb;        // r = r^2 * rsq(r^2)
      // FENE: -0.5*eps*log1p(-arg), eps=2 -> -log(1-arg); delta=0.25 -> *4
      float u = (rbb - 0.7525f) * 4.0f;
      float arg = fminf(u * u, 0.999999f);
      e += -__logf(1.f - arg);
      // stacking
      float rsss = arsq(rss2);
      float rss  = rss2 * rsss;
      float f1v = f1f(rss, P.f1_stck);
      if (f1v != 0.f) {
        V3 a2i, a3i, a2j, a3j;
        quat_a23(qi, a2i, a3i);
        quat_a23(qj, a2j, a3j);
        V3 rhs = rsss * dss;
        V3 rhb = rsbb * dbb;
        float th4 = acosc( dot(a3i, a3j));
        float th5 = acosc( dot(rhs, a3j));
        float th6 = acosc(-dot(rhs, a3i));
        e += seps[gid - M] * f1v * f4f(th4, P.s4) * f4f(th5, P.s5) * f4f(th6, P.s5)
                           * f5f(dot(a2i, rhb), P.f5) * f5f(dot(a2j, rhb), P.f5);
      }
    }
  }

  // ---- in-block compaction of angle-needing NB pairs (atomic-free) ----
  __shared__ unsigned wcnt[4];
  __shared__ int2 spair[256];
  int lane = threadIdx.x & 63, wid = threadIdx.x >> 6;
  unsigned long long mask = __ballot(need);
  if (lane == 0) wcnt[wid] = (unsigned)__popcll(mask);
  __syncthreads();
  unsigned base = 0;
  #pragma unroll
  for (int w = 0; w < 4; ++w) if (w < wid) base += wcnt[w];
  unsigned total = wcnt[0] + wcnt[1] + wcnt[2] + wcnt[3];
  if (need) {
    unsigned pfx = (unsigned)__popcll(mask & ((1ull << lane) - 1ull));
    spair[base + pfx] = myij;
  }
  __syncthreads();

  // ---- dense angle phase: ~all lanes useful ----
  for (unsigned t = threadIdx.x; t < total; t += 256) {
    int2 ij = spair[t];
    float4 pi4 = rec[2*ij.x], qi = rec[2*ij.x+1];
    float4 pj4 = rec[2*ij.y], qj = rec[2*ij.y+1];
    V3 dp = { pj4.x - pi4.x, pj4.y - pi4.y, pj4.z - pi4.z };
    V3 a1i, a2i, a3i, a1j, a2j, a3j;
    quat_a1(qi, a1i);  quat_a23(qi, a2i, a3i);
    quat_a1(qj, a1j);  quat_a23(qj, a2j, a3j);
    V3 s = a1j - a1i;
    V3 dhh = mim(dp + 0.4f  * s, box, ibox);
    V3 dss = mim(dp + 0.34f * s, box, ibox);
    float rhh2 = dot(dhh, dhh) + 1e-12f;
    float rss2 = dot(dss, dss) + 1e-12f;
    float rsh = arsq(rhh2);
    float rhh = rhh2 * rsh;

    float t1 = acosc(-dot(a1i, a1j));
    float t4 = acosc( dot(a3i, a3j));

    V3 rh = rsh * dhh;
    float t2 = acosc(-dot(rh, a1j));
    float t3 = acosc( dot(rh, a1i));
    float t7 = acosc(-dot(rh, a3j));
    float t8 = acosc( dot(rh, a3i));

    float f1v = f1f(rhh, P.f1_hb);
    if (f1v != 0.f) {
      int bti = __float_as_int(pi4.w), btj = __float_as_int(pj4.w);
      float eps = hbm[bti * 4 + btj];
      e += eps * f1v * f4f(t1, P.h1) * f4f(t2, P.h1) * f4f(t3, P.h1)
               * f4f(t4, P.h4) * f4f(t7, P.h7) * f4f(t8, P.h7);
    }
    float f2v = f2f(rhh, P.f2_crst);
    if (f2v != 0.f)
      e += f2v * f4f(t1, P.c1) * f4f(t2, P.c2) * f4f(t3, P.c2)
               * f4f(t4, P.h1) * f4f(t7, P.c7) * f4f(t8, P.c7);

    float rsx = arsq(rss2);
    float rss = rss2 * rsx;
    float f2x = f2f(rss, P.f2_cx);
    if (f2x != 0.f) {
      V3 rx = rsx * dss;
      e += f2x * f4f(t1, P.x1) * f4f(t4, P.s4)
               * f5f(dot(a2i, rx), P.f5) * f5f(dot(a2j, rx), P.f5);
    }
  }

  // deterministic block reduction in double
  double v = (double)e;
  #pragma unroll
  for (int off = 32; off > 0; off >>= 1) v += __shfl_down(v, off, 64);
  __shared__ double sm[4];
  if (lane == 0) sm[wid] = v;
  __syncthreads();
  if (threadIdx.x == 0) partials[blockIdx.x] = sm[0] + sm[1] + sm[2] + sm[3];
}

__global__ void __launch_bounds__(1024)
finalize_kernel(const double* __restrict__ part, int n, float* __restrict__ out) {
  double v = 0.0;
  for (int i = threadIdx.x; i < n; i += 1024) v += part[i];
  #pragma unroll
  for (int off = 32; off > 0; off >>= 1) v += __shfl_down(v, off, 64);
  __shared__ double sm[16];
  int lane = threadIdx.x & 63, wid = threadIdx.x >> 6;
  if (lane == 0) sm[wid] = v;
  __syncthreads();
  if (wid == 0) {
    v = (lane < 16) ? sm[lane] : 0.0;
    #pragma unroll
    for (int off = 8; off > 0; off >>= 1) v += __shfl_down(v, off, 64);
    if (lane == 0) out[0] = (float)v;
  }
}

// ---------------- host-side constant construction (double precision) ----------------
static inline double sqd(double x) { return x * x; }

static F1C mkf1(double a, double r0, double rc, double rlow, double rhigh) {
  double shift = sqd(1.0 - exp(-a * (rc - r0)));
  double el = exp(-a * (rlow - r0)), eh = exp(-a * (rhigh - r0));
  double Vl = sqd(1.0 - el) - shift, Vh = sqd(1.0 - eh) - shift;
  double dVl = 2.0 * (1.0 - el) * a * el, dVh = 2.0 * (1.0 - eh) * a * eh;
  double rclow = rlow - 2.0 * Vl / dVl, blow = dVl * dVl / (4.0 * Vl);
  double rchigh = rhigh - 2.0 * Vh / dVh, bhigh = dVh * dVh / (4.0 * Vh);
  return { (float)a, (float)r0, (float)shift, (float)rlow, (float)rhigh,
           (float)blow, (float)rclow, (float)bhigh, (float)rchigh };
}

static F2C mkf2(double k, double r0, double rc, double rlow, double rhigh) {
  double dc2 = sqd(rc - r0);
  double Vl = 0.5 * k * (sqd(rlow - r0) - dc2), Vh = 0.5 * k * (sqd(rhigh - r0) - dc2);
  double dVl = k * (rlow - r0), dVh = k * (rhigh - r0);
  double rclow = rlow - 2.0 * Vl / dVl, blow = dVl * dVl / (4.0 * Vl);
  double rchigh = rhigh - 2.0 * Vh / dVh, bhigh = dVh * dVh / (4.0 * Vh);
  return { (float)k, (float)r0, (float)dc2, (float)rlow, (float)rhigh,
           (float)blow, (float)rclow, (float)bhigh, (float)rchigh };
}

static F3C mkf3(double sigma, double rstar) {
  double s6 = pow(sigma, 6.0);
  double V = 4.0 * (s6 * s6 / pow(rstar, 12.0) - s6 / pow(rstar, 6.0));
  double dV = 4.0 * (-12.0 * s6 * s6 / pow(rstar, 13.0) + 6.0 * s6 / pow(rstar, 7.0));
  double rc = rstar - 2.0 * V / dV, b = dV * dV / (4.0 * V);
  return { (float)(sigma * sigma), (float)(rstar * rstar), (float)b,
           (float)rc, (float)(rc * rc) };
}

static F4C mkf4(double a, double t0, double ts) {
  double b = a * a * ts * ts / (1.0 - a * ts * ts);
  double tc = ts + a * ts / b;
  return { (float)a, (float)t0, (float)ts, (float)b, (float)tc };
}

static F5P mkf5(double a, double xs) {
  double V = 1.0 - a * xs * xs, dV = -2.0 * a * xs;
  double xc = xs - 2.0 * V / dV, b = dV * dV / (4.0 * V);
  return { (float)a, (float)xs, (float)xc, (float)b };
}

extern "C" void kernel_launch(void* const* d_in, const int* in_sizes, int n_in,
                              void* d_out, int out_size, void* d_ws, size_t ws_size,
                              hipStream_t stream) {
  (void)n_in; (void)out_size; (void)ws_size;
  const double PI = 3.141592653589793;

  const float*  pos  = (const float*)d_in[0];
  const float4* quat = (const float4*)d_in[1];
  const float*  box  = (const float*)d_in[2];
  const float*  seps = (const float*)d_in[3];
  const float*  hbm  = (const float*)d_in[4];
  const float*  excl = (const float*)d_in[5];
  const int2*   bp   = (const int2*)d_in[6];
  const int2*   nbp  = (const int2*)d_in[7];
  const int*    bt   = (const int*)d_in[8];

  int N  = in_sizes[0] / 3;     // particles
  int NP = in_sizes[6] / 2;     // bonded pairs
  int M  = in_sizes[7] / 2;     // nonbonded pairs
  int total = M + NP;
  int blocks = (total + 255) / 256;

  Params P;
  P.f1_stck = mkf1(6.0, 0.4, 0.9, 0.32, 0.75);
  P.f1_hb   = mkf1(8.0, 0.4, 0.75, 0.34, 0.7);
  P.f2_crst = mkf2(47.5, 0.575, 0.675, 0.495, 0.655);
  P.f2_cx   = mkf2(46.0, 0.4, 0.6, 0.22, 0.58);
  P.f3_back = mkf3(0.7, 0.675);
  P.f3_base = mkf3(0.33, 0.32);
  P.f3_mix  = mkf3(0.515, 0.5);
  P.s4 = mkf4(1.3, 0.0, 0.8);
  P.s5 = mkf4(0.9, 0.0, 0.95);
  P.h1 = mkf4(1.5, 0.0, 0.7);
  P.h4 = mkf4(0.46, PI, 0.7);
  P.h7 = mkf4(4.0, 0.5 * PI, 0.45);
  P.c1 = mkf4(2.25, 0.791, 0.58);
  P.c2 = mkf4(1.7, 1.003, 0.68);
  P.c7 = mkf4(1.7, 0.555, 0.68);
  P.x1 = mkf4(2.0, 2.592, 0.65);
  P.f5 = mkf5(2.0, -0.65);
  // compaction windows, padded then squared (gates compare against r^2)
  {
    double lo1 = (double)P.f1_hb.rclow  - 1e-3, hi1 = (double)P.f1_hb.rchigh + 1e-3;
    double lo2 = (double)P.f2_cx.rclow  - 1e-3, hi2 = (double)P.f2_cx.rchigh + 1e-3;
    P.nlo1sq = (float)(lo1 * lo1);  P.nhi1sq = (float)(hi1 * hi1);
    P.nlo2sq = (float)(lo2 * lo2);  P.nhi2sq = (float)(hi2 * hi2);
  }

  // ws layout: [0, 2MB) packed records | [4MB, ...) partials
  float4* rec       = (float4*)d_ws;
  double* partials  = (double*)((char*)d_ws + (4u << 20));

  pack_kernel<<<(N + 255) / 256, 256, 0, stream>>>(pos, quat, bt, N, rec);
  energy_kernel<<<blocks, 256, 0, stream>>>(rec, box, seps, hbm, excl,
                                            bp, nbp, M, NP, P, partials);
  finalize_kernel<<<1, 1024, 0, stream>>>(partials, blocks, (float*)d_out);
}